// Round 6
// baseline (1480.354 us; speedup 1.0000x reference)
//
#include <hip/hip_runtime.h>
#include <math.h>

// T=1000, B=256, F_IN=13 x3 -> 39 features, H=100, gates r,z,n (3H=300), 20 classes
#define T_STEPS 1000
#define BATCH   256
#define FIN     13
#define XDIM    39
#define HDIM    100
#define NCLS    20

#define NCONS   832     // 13 consumer waves: 8 lanes per hidden unit, 16-col parts
#define NTHR    1024    // + 3 producer waves (192 threads, 150 active)
#define SLDS    20      // part stride in floats (16 cols + 4 skew) -> disjoint banks
#define HPAD2   160     // 8 parts * SLDS

__device__ __forceinline__ float fast_sigmoid(float v) {
    return 1.f / (1.f + __expf(-v));
}
// quad_perm butterflies (VALU DPP)
__device__ __forceinline__ float quad_xor1(float v) {
    return __int_as_float(__builtin_amdgcn_update_dpp(0, __float_as_int(v), 0xB1, 0xF, 0xF, true)); // [1,0,3,2]
}
__device__ __forceinline__ float quad_xor2(float v) {
    return __int_as_float(__builtin_amdgcn_update_dpp(0, __float_as_int(v), 0x4E, 0xF, 0xF, true)); // [2,3,0,1]
}
// lane l <-> l^4 (crosses quads, within 8-lane unit group)
__device__ __forceinline__ float swz_xor4(float v) {
    return __int_as_float(__builtin_amdgcn_ds_swizzle(__float_as_int(v), 0x101F));
}

// R4/R5 lesson: for B=1024 the compiler's default (and the (1024,2) hint) target
// 8 waves/SIMD -> 64-VGPR cap -> ~90-float weight set spills to scratch
// (WRITE_SIZE 12-47 MB, dur 1175-1474). Fix: __launch_bounds__(1024, 4) pins
// 1 block/CU = 4 waves/SIMD -> 128-VGPR cap (also the HW max for B=1024),
// need ~110 -> no spill. gib stays flat (bank conflicts measured 0 in R5).
__launch_bounds__(NTHR, 4)
__global__ void gru_persistent(const float* __restrict__ mfcc0,
                               const float* __restrict__ mfcc1,
                               const float* __restrict__ mfcc2,
                               const float* __restrict__ len0,
                               const float* __restrict__ W_ih,
                               const float* __restrict__ W_hh,
                               const float* __restrict__ b_ih,
                               const float* __restrict__ b_hh,
                               const float* __restrict__ W_out,
                               const float* __restrict__ b_out,
                               float* __restrict__ out)
{
    const int b   = blockIdx.x;
    const int tid = threadIdx.x;

    __shared__ __align__(16) float Vh2[2][HPAD2];     // h(t): part p at [20p..20p+15], skew pad
    __shared__ __align__(16) float gib[2][304];       // gi flat: [g*100 + j]
    __shared__ __align__(16) float xbuf[2][40];       // x staging (39 + zero pad)
    __shared__ float feat[2 * HDIM];

    const bool isCons = (tid < NCONS);

    // ---- consumer geometry: 8-lane group = hidden unit j, lane part p ----
    const int ju = tid >> 3;                    // 0..103 (consumers), idle >=100
    const int p  = tid & 7;                     // column part (16 cols each)
    const int j  = (ju < HDIM) ? ju : (HDIM - 1);

    // ---- producer geometry: rows (gA, gA+1) of the 300 gi rows ----
    const int q0 = isCons ? 0 : (tid - NCONS);  // 0..191, active <150
    const int gA = 2 * ((q0 < 150) ? q0 : 149);
    const int gB = gA + 1;

    // ---- SHARED weight registers: consumers w[0..11], producers w[0..19] ----
    float4 w[20];
    float  bh0 = 0.f, bh1 = 0.f, bh2 = 0.f;     // consumer: b_hh triple; producer: b_ih pair
    if (isCons) {
        const int base = 16 * p;
        #pragma unroll
        for (int rr = 0; rr < 3; ++rr) {
            const float* src = W_hh + (rr * HDIM + j) * HDIM;
            #pragma unroll
            for (int i = 0; i < 4; ++i) {
                const int c = base + 4 * i;
                float4 t;
                t.x = (c + 0 < HDIM) ? src[c + 0] : 0.f;
                t.y = (c + 1 < HDIM) ? src[c + 1] : 0.f;
                t.z = (c + 2 < HDIM) ? src[c + 2] : 0.f;
                t.w = (c + 3 < HDIM) ? src[c + 3] : 0.f;
                w[rr * 4 + i] = t;
            }
        }
        bh0 = b_hh[j]; bh1 = b_hh[HDIM + j]; bh2 = b_hh[2 * HDIM + j];
    } else {
        const float* sA = W_ih + gA * XDIM;
        const float* sB = W_ih + gB * XDIM;
        #pragma unroll
        for (int i = 0; i < 9; ++i) {
            w[i]      = make_float4(sA[4*i], sA[4*i+1], sA[4*i+2], sA[4*i+3]);
            w[10 + i] = make_float4(sB[4*i], sB[4*i+1], sB[4*i+2], sB[4*i+3]);
        }
        w[9]  = make_float4(sA[36], sA[37], sA[38], 0.f);   // pairs with xbuf[39]=0
        w[19] = make_float4(sB[36], sB[37], sB[38], 0.f);
        bh0 = b_ih[gA]; bh1 = b_ih[gB];
    }

    // ---- producer x streaming source ----
    const float* xsrc = mfcc0;
    int xoff = b * FIN;
    if (!isCons && q0 < XDIM) {
        const int f = q0 % FIN;
        xsrc = (q0 < FIN) ? mfcc0 : (q0 < 2 * FIN ? mfcc1 : mfcc2);
        xoff = b * FIN + f;
    }

    // ---- prologue: h0 = 0 (both buffers incl. skew pads), stage x(0)/x(1), gi(0) ----
    if (tid < HPAD2) { Vh2[0][tid] = 0.f; Vh2[1][tid] = 0.f; }
    if (tid < 40) {
        float v0 = 0.f, v1 = 0.f;
        if (tid < XDIM) {
            const int f = tid % FIN;
            const float* xs = (tid < FIN) ? mfcc0 : (tid < 2 * FIN ? mfcc1 : mfcc2);
            v0 = xs[b * FIN + f];
            v1 = xs[(size_t)BATCH * FIN + b * FIN + f];
        }
        xbuf[0][tid] = v0; xbuf[1][tid] = v1;
    }
    __syncthreads();
    if (!isCons && q0 < 150) {
        const float4* X4 = (const float4*)xbuf[0];
        float a0=0,a1=0,a2=0,a3=0, c0=0,c1=0,c2=0,c3=0;
        #pragma unroll
        for (int i = 0; i < 10; ++i) {
            const float4 vv = X4[i];
            a0=fmaf(w[i].x,vv.x,a0);      a1=fmaf(w[i].y,vv.y,a1);
            a2=fmaf(w[i].z,vv.z,a2);      a3=fmaf(w[i].w,vv.w,a3);
            c0=fmaf(w[10+i].x,vv.x,c0);   c1=fmaf(w[10+i].y,vv.y,c1);
            c2=fmaf(w[10+i].z,vv.z,c2);   c3=fmaf(w[10+i].w,vv.w,c3);
        }
        gib[0][gA] = bh0 + ((a0+a1)+(a2+a3));
        gib[0][gB] = bh1 + ((c0+c1)+(c2+c3));
    }
    __syncthreads();

    float hreg = 0.f;                 // h_j, replicated in all 8 unit lanes
    float sum = 0.f, mx = -INFINITY;
    const int hdst = SLDS * (j >> 4) + (j & 15);   // col j LDS address

    for (int t = 0; t < T_STEPS; ++t) {
        const int cur = t & 1;
        const int nxt = cur ^ 1;

        if (isCons) {
            // ---- GEMV part: 4 bcast float4 reads (skewed banks), 3 gates x 16 cols ----
            const float4* V4 = (const float4*)(Vh2[cur] + SLDS * p);
            float a0=0,a1=0,a2=0,a3=0, b0=0,b1=0,b2=0,b3=0, c0=0,c1=0,c2=0,c3=0;
            #pragma unroll
            for (int i = 0; i < 4; ++i) {
                const float4 vv = V4[i];
                a0=fmaf(w[i].x,vv.x,a0);      a1=fmaf(w[i].y,vv.y,a1);
                a2=fmaf(w[i].z,vv.z,a2);      a3=fmaf(w[i].w,vv.w,a3);
                b0=fmaf(w[4+i].x,vv.x,b0);    b1=fmaf(w[4+i].y,vv.y,b1);
                b2=fmaf(w[4+i].z,vv.z,b2);    b3=fmaf(w[4+i].w,vv.w,b3);
                c0=fmaf(w[8+i].x,vv.x,c0);    c1=fmaf(w[8+i].y,vv.y,c1);
                c2=fmaf(w[8+i].z,vv.z,c2);    c3=fmaf(w[8+i].w,vv.w,c3);
            }
            float s0 = (a0+a1)+(a2+a3);
            float s1 = (b0+b1)+(b2+b3);
            float s2 = (c0+c1)+(c2+c3);
            // ---- 8-lane butterfly: 2x DPP quad + 1x ds_swizzle xor4 ----
            s0 += quad_xor1(s0); s1 += quad_xor1(s1); s2 += quad_xor1(s2);
            s0 += quad_xor2(s0); s1 += quad_xor2(s1); s2 += quad_xor2(s2);
            s0 += swz_xor4(s0);  s1 += swz_xor4(s1);  s2 += swz_xor4(s2);
            // ---- gates + state update, fully in-register ----
            const float gr = gib[cur][j];
            const float gz = gib[cur][HDIM + j];
            const float gn = gib[cur][2 * HDIM + j];
            const float rg = fast_sigmoid(gr + s0 + bh0);
            const float zg = fast_sigmoid(gz + s1 + bh1);
            const float na = fmaf(rg, s2 + bh2, gn);
            const float ng = fmaf(2.f, fast_sigmoid(2.f * na), -1.f);  // tanh
            const float hv = fmaf(zg, hreg - ng, ng);              // (1-z)*n + z*h
            hreg = hv;
            sum += hv; mx = fmaxf(mx, hv);
            if (p == 0 && ju < HDIM) Vh2[nxt][hdst] = hv;          // publish h(t+1)
        } else {
            // ---- producers: prefetch x(t+2), compute gi(t+1) into gib[nxt] ----
            float xv = 0.f;
            const bool doX = (q0 < XDIM) && (t + 2 < T_STEPS);
            if (doX) xv = xsrc[(size_t)(t + 2) * (BATCH * FIN) + xoff];
            if ((t + 1 < T_STEPS) && q0 < 150) {
                const float4* X4 = (const float4*)xbuf[nxt];
                float a0=0,a1=0,a2=0,a3=0, c0=0,c1=0,c2=0,c3=0;
                #pragma unroll
                for (int i = 0; i < 10; ++i) {
                    const float4 vv = X4[i];
                    a0=fmaf(w[i].x,vv.x,a0);      a1=fmaf(w[i].y,vv.y,a1);
                    a2=fmaf(w[i].z,vv.z,a2);      a3=fmaf(w[i].w,vv.w,a3);
                    c0=fmaf(w[10+i].x,vv.x,c0);   c1=fmaf(w[10+i].y,vv.y,c1);
                    c2=fmaf(w[10+i].z,vv.z,c2);   c3=fmaf(w[10+i].w,vv.w,c3);
                }
                gib[nxt][gA] = bh0 + ((a0+a1)+(a2+a3));
                gib[nxt][gB] = bh1 + ((c0+c1)+(c2+c3));
            }
            if (doX) xbuf[cur][q0] = xv;
        }
        __syncthreads();
    }

    // ---- pooling + output linear ----
    if (isCons && p == 0 && ju < HDIM) {
        feat[ju]        = sum / len0[b];
        feat[HDIM + ju] = mx;
    }
    __syncthreads();

    if (tid < NCLS) {
        float acc = b_out[tid];
        #pragma unroll 4
        for (int k = 0; k < 2 * HDIM; ++k)
            acc = fmaf(W_out[tid * 2 * HDIM + k], feat[k], acc);
        out[b * NCLS + tid] = acc;
    }
}

extern "C" void kernel_launch(void* const* d_in, const int* in_sizes, int n_in,
                              void* d_out, int out_size, void* d_ws, size_t ws_size,
                              hipStream_t stream)
{
    const float* mfcc0 = (const float*)d_in[0];
    const float* mfcc1 = (const float*)d_in[1];
    const float* mfcc2 = (const float*)d_in[2];
    const float* len0  = (const float*)d_in[3];
    const float* W_ih  = (const float*)d_in[4];
    const float* W_hh  = (const float*)d_in[5];
    const float* b_ih  = (const float*)d_in[6];
    const float* b_hh  = (const float*)d_in[7];
    const float* W_out = (const float*)d_in[8];
    const float* b_out = (const float*)d_in[9];
    float* out = (float*)d_out;

    gru_persistent<<<BATCH, NTHR, 0, stream>>>(
        mfcc0, mfcc1, mfcc2, len0, W_ih, W_hh, b_ih, b_hh, W_out, b_out, out);
}

// Round 7
// 1478.868 us; speedup vs baseline: 1.0010x; 1.0010x over previous
//
#include <hip/hip_runtime.h>
#include <math.h>

// T=1000, B=256, F_IN=13 x3 -> 39 features, H=100, gates r,z,n (3H=300), 20 classes
#define T_STEPS 1000
#define BATCH   256
#define FIN     13
#define XDIM    39
#define HDIM    100
#define NCLS    20

#define NCONS   832     // 13 consumer waves: 8 lanes per hidden unit, 16-col parts
#define NTHR    1024    // + 3 producer waves (192 threads, 150 active)
#define SLDS    20      // part stride in floats (16 cols + 4 skew) -> disjoint banks
#define HPAD2   160     // 8 parts * SLDS

__device__ __forceinline__ float fast_sigmoid(float v) {
    return 1.f / (1.f + __expf(-v));
}
// quad_perm butterflies (VALU DPP)
__device__ __forceinline__ float quad_xor1(float v) {
    return __int_as_float(__builtin_amdgcn_update_dpp(0, __float_as_int(v), 0xB1, 0xF, 0xF, true)); // [1,0,3,2]
}
__device__ __forceinline__ float quad_xor2(float v) {
    return __int_as_float(__builtin_amdgcn_update_dpp(0, __float_as_int(v), 0x4E, 0xF, 0xF, true)); // [2,3,0,1]
}
// lane l <-> l^4 (crosses quads, within 8-lane unit group)
__device__ __forceinline__ float swz_xor4(float v) {
    return __int_as_float(__builtin_amdgcn_ds_swizzle(__float_as_int(v), 0x101F));
}

// R4/R5/R6 lesson: __launch_bounds__ second arg only RAISES the occupancy floor
// (lowers the VGPR cap); it never stops the allocator from going BELOW the cap
// for more waves. For B=1024 the heuristic targets 8 waves/SIMD -> 64 VGPR and
// spills the ~90-float weight set (WRITE_SIZE 47MB, 3 rounds in a row).
// Fix: amdgpu_waves_per_eu(4,4) bounds occupancy from ABOVE -> nothing to gain
// past 4 waves/SIMD -> allocator may use 512/4 = 128 VGPR -> weights resident.
// (grid = 256 blocks = 1 block/CU; a 16-wave block needs exactly 4 waves/SIMD,
// so max=4 costs zero real occupancy.)
__attribute__((amdgpu_flat_work_group_size(NTHR, NTHR), amdgpu_waves_per_eu(4, 4)))
__global__ void gru_persistent(const float* __restrict__ mfcc0,
                               const float* __restrict__ mfcc1,
                               const float* __restrict__ mfcc2,
                               const float* __restrict__ len0,
                               const float* __restrict__ W_ih,
                               const float* __restrict__ W_hh,
                               const float* __restrict__ b_ih,
                               const float* __restrict__ b_hh,
                               const float* __restrict__ W_out,
                               const float* __restrict__ b_out,
                               float* __restrict__ out)
{
    const int b   = blockIdx.x;
    const int tid = threadIdx.x;

    __shared__ __align__(16) float Vh2[2][HPAD2];     // h(t): part p at [20p..20p+15], skew pad
    __shared__ __align__(16) float gib[2][304];       // gi flat: [g*100 + j]
    __shared__ __align__(16) float xbuf[2][40];       // x staging (39 + zero pad)
    __shared__ float feat[2 * HDIM];

    const bool isCons = (tid < NCONS);

    // ---- consumer geometry: 8-lane group = hidden unit j, lane part p ----
    const int ju = tid >> 3;                    // 0..103 (consumers), idle >=100
    const int p  = tid & 7;                     // column part (16 cols each)
    const int j  = (ju < HDIM) ? ju : (HDIM - 1);

    // ---- producer geometry: rows (gA, gA+1) of the 300 gi rows ----
    const int q0 = isCons ? 0 : (tid - NCONS);  // 0..191, active <150
    const int gA = 2 * ((q0 < 150) ? q0 : 149);
    const int gB = gA + 1;

    // ---- SHARED weight registers: consumers w[0..11], producers w[0..19] ----
    float4 w[20];
    float  bh0 = 0.f, bh1 = 0.f, bh2 = 0.f;     // consumer: b_hh triple; producer: b_ih pair
    if (isCons) {
        const int base = 16 * p;
        #pragma unroll
        for (int rr = 0; rr < 3; ++rr) {
            const float* src = W_hh + (rr * HDIM + j) * HDIM;
            #pragma unroll
            for (int i = 0; i < 4; ++i) {
                const int c = base + 4 * i;
                float4 t;
                t.x = (c + 0 < HDIM) ? src[c + 0] : 0.f;
                t.y = (c + 1 < HDIM) ? src[c + 1] : 0.f;
                t.z = (c + 2 < HDIM) ? src[c + 2] : 0.f;
                t.w = (c + 3 < HDIM) ? src[c + 3] : 0.f;
                w[rr * 4 + i] = t;
            }
        }
        bh0 = b_hh[j]; bh1 = b_hh[HDIM + j]; bh2 = b_hh[2 * HDIM + j];
    } else {
        const float* sA = W_ih + gA * XDIM;
        const float* sB = W_ih + gB * XDIM;
        #pragma unroll
        for (int i = 0; i < 9; ++i) {
            w[i]      = make_float4(sA[4*i], sA[4*i+1], sA[4*i+2], sA[4*i+3]);
            w[10 + i] = make_float4(sB[4*i], sB[4*i+1], sB[4*i+2], sB[4*i+3]);
        }
        w[9]  = make_float4(sA[36], sA[37], sA[38], 0.f);   // pairs with xbuf[39]=0
        w[19] = make_float4(sB[36], sB[37], sB[38], 0.f);
        bh0 = b_ih[gA]; bh1 = b_ih[gB];
    }

    // ---- producer x streaming source ----
    const float* xsrc = mfcc0;
    int xoff = b * FIN;
    if (!isCons && q0 < XDIM) {
        const int f = q0 % FIN;
        xsrc = (q0 < FIN) ? mfcc0 : (q0 < 2 * FIN ? mfcc1 : mfcc2);
        xoff = b * FIN + f;
    }

    // ---- prologue: h0 = 0 (both buffers incl. skew pads), stage x(0)/x(1), gi(0) ----
    if (tid < HPAD2) { Vh2[0][tid] = 0.f; Vh2[1][tid] = 0.f; }
    if (tid < 40) {
        float v0 = 0.f, v1 = 0.f;
        if (tid < XDIM) {
            const int f = tid % FIN;
            const float* xs = (tid < FIN) ? mfcc0 : (tid < 2 * FIN ? mfcc1 : mfcc2);
            v0 = xs[b * FIN + f];
            v1 = xs[(size_t)BATCH * FIN + b * FIN + f];
        }
        xbuf[0][tid] = v0; xbuf[1][tid] = v1;
    }
    __syncthreads();
    if (!isCons && q0 < 150) {
        const float4* X4 = (const float4*)xbuf[0];
        float a0=0,a1=0,a2=0,a3=0, c0=0,c1=0,c2=0,c3=0;
        #pragma unroll
        for (int i = 0; i < 10; ++i) {
            const float4 vv = X4[i];
            a0=fmaf(w[i].x,vv.x,a0);      a1=fmaf(w[i].y,vv.y,a1);
            a2=fmaf(w[i].z,vv.z,a2);      a3=fmaf(w[i].w,vv.w,a3);
            c0=fmaf(w[10+i].x,vv.x,c0);   c1=fmaf(w[10+i].y,vv.y,c1);
            c2=fmaf(w[10+i].z,vv.z,c2);   c3=fmaf(w[10+i].w,vv.w,c3);
        }
        gib[0][gA] = bh0 + ((a0+a1)+(a2+a3));
        gib[0][gB] = bh1 + ((c0+c1)+(c2+c3));
    }
    __syncthreads();

    float hreg = 0.f;                 // h_j, replicated in all 8 unit lanes
    float sum = 0.f, mx = -INFINITY;
    const int hdst = SLDS * (j >> 4) + (j & 15);   // col j LDS address

    for (int t = 0; t < T_STEPS; ++t) {
        const int cur = t & 1;
        const int nxt = cur ^ 1;

        if (isCons) {
            // ---- GEMV part: 4 bcast float4 reads (skewed banks), 3 gates x 16 cols ----
            const float4* V4 = (const float4*)(Vh2[cur] + SLDS * p);
            float a0=0,a1=0,a2=0,a3=0, b0=0,b1=0,b2=0,b3=0, c0=0,c1=0,c2=0,c3=0;
            #pragma unroll
            for (int i = 0; i < 4; ++i) {
                const float4 vv = V4[i];
                a0=fmaf(w[i].x,vv.x,a0);      a1=fmaf(w[i].y,vv.y,a1);
                a2=fmaf(w[i].z,vv.z,a2);      a3=fmaf(w[i].w,vv.w,a3);
                b0=fmaf(w[4+i].x,vv.x,b0);    b1=fmaf(w[4+i].y,vv.y,b1);
                b2=fmaf(w[4+i].z,vv.z,b2);    b3=fmaf(w[4+i].w,vv.w,b3);
                c0=fmaf(w[8+i].x,vv.x,c0);    c1=fmaf(w[8+i].y,vv.y,c1);
                c2=fmaf(w[8+i].z,vv.z,c2);    c3=fmaf(w[8+i].w,vv.w,c3);
            }
            float s0 = (a0+a1)+(a2+a3);
            float s1 = (b0+b1)+(b2+b3);
            float s2 = (c0+c1)+(c2+c3);
            // ---- 8-lane butterfly: 2x DPP quad + 1x ds_swizzle xor4 ----
            s0 += quad_xor1(s0); s1 += quad_xor1(s1); s2 += quad_xor1(s2);
            s0 += quad_xor2(s0); s1 += quad_xor2(s1); s2 += quad_xor2(s2);
            s0 += swz_xor4(s0);  s1 += swz_xor4(s1);  s2 += swz_xor4(s2);
            // ---- gates + state update, fully in-register ----
            const float gr = gib[cur][j];
            const float gz = gib[cur][HDIM + j];
            const float gn = gib[cur][2 * HDIM + j];
            const float rg = fast_sigmoid(gr + s0 + bh0);
            const float zg = fast_sigmoid(gz + s1 + bh1);
            const float na = fmaf(rg, s2 + bh2, gn);
            const float ng = fmaf(2.f, fast_sigmoid(2.f * na), -1.f);  // tanh
            const float hv = fmaf(zg, hreg - ng, ng);              // (1-z)*n + z*h
            hreg = hv;
            sum += hv; mx = fmaxf(mx, hv);
            if (p == 0 && ju < HDIM) Vh2[nxt][hdst] = hv;          // publish h(t+1)
        } else {
            // ---- producers: prefetch x(t+2), compute gi(t+1) into gib[nxt] ----
            float xv = 0.f;
            const bool doX = (q0 < XDIM) && (t + 2 < T_STEPS);
            if (doX) xv = xsrc[(size_t)(t + 2) * (BATCH * FIN) + xoff];
            if ((t + 1 < T_STEPS) && q0 < 150) {
                const float4* X4 = (const float4*)xbuf[nxt];
                float a0=0,a1=0,a2=0,a3=0, c0=0,c1=0,c2=0,c3=0;
                #pragma unroll
                for (int i = 0; i < 10; ++i) {
                    const float4 vv = X4[i];
                    a0=fmaf(w[i].x,vv.x,a0);      a1=fmaf(w[i].y,vv.y,a1);
                    a2=fmaf(w[i].z,vv.z,a2);      a3=fmaf(w[i].w,vv.w,a3);
                    c0=fmaf(w[10+i].x,vv.x,c0);   c1=fmaf(w[10+i].y,vv.y,c1);
                    c2=fmaf(w[10+i].z,vv.z,c2);   c3=fmaf(w[10+i].w,vv.w,c3);
                }
                gib[nxt][gA] = bh0 + ((a0+a1)+(a2+a3));
                gib[nxt][gB] = bh1 + ((c0+c1)+(c2+c3));
            }
            if (doX) xbuf[cur][q0] = xv;
        }
        __syncthreads();
    }

    // ---- pooling + output linear ----
    if (isCons && p == 0 && ju < HDIM) {
        feat[ju]        = sum / len0[b];
        feat[HDIM + ju] = mx;
    }
    __syncthreads();

    if (tid < NCLS) {
        float acc = b_out[tid];
        #pragma unroll 4
        for (int k = 0; k < 2 * HDIM; ++k)
            acc = fmaf(W_out[tid * 2 * HDIM + k], feat[k], acc);
        out[b * NCLS + tid] = acc;
    }
}

extern "C" void kernel_launch(void* const* d_in, const int* in_sizes, int n_in,
                              void* d_out, int out_size, void* d_ws, size_t ws_size,
                              hipStream_t stream)
{
    const float* mfcc0 = (const float*)d_in[0];
    const float* mfcc1 = (const float*)d_in[1];
    const float* mfcc2 = (const float*)d_in[2];
    const float* len0  = (const float*)d_in[3];
    const float* W_ih  = (const float*)d_in[4];
    const float* W_hh  = (const float*)d_in[5];
    const float* b_ih  = (const float*)d_in[6];
    const float* b_hh  = (const float*)d_in[7];
    const float* W_out = (const float*)d_in[8];
    const float* b_out = (const float*)d_in[9];
    float* out = (float*)d_out;

    gru_persistent<<<BATCH, NTHR, 0, stream>>>(
        mfcc0, mfcc1, mfcc2, len0, W_ih, W_hh, b_ih, b_hh, W_out, b_out, out);
}

// Round 8
// 1474.426 us; speedup vs baseline: 1.0040x; 1.0030x over previous
//
#include <hip/hip_runtime.h>
#include <math.h>

// T=1000, B=256, F_IN=13 x3 -> 39 features, H=100, gates r,z,n (3H=300), 20 classes
#define T_STEPS 1000
#define BATCH   256
#define FIN     13
#define XDIM    39
#define HDIM    100
#define NCLS    20

#define NCONS   832     // 13 consumer waves: 8 lanes per hidden unit, 16-col parts
#define NTHR    1024    // + 3 producer waves (192 threads, 150 active)
#define SLDS    20      // part stride in floats (16 cols + 4 skew) -> disjoint banks
#define HPAD2   160     // 8 parts * SLDS

// 84 KB static LDS pool: buffers live in the first ~1.2K floats; the REST is
// deliberate padding. Purpose: static LDS > 80 KB forces the compile-time
// occupancy model to 1 block/CU (160 KB LDS on gfx950) -> achievable occupancy
// = 16 waves/4 SIMD = 4 waves/EU -> VGPR budget 512/4 = 128 -> the ~90-float
// weight set stays in registers. (R4-R7: with 5 KB LDS the heuristic assumed
// 2 blocks/CU = 8 waves/EU -> 64 VGPR -> 47 MB scratch spill, dur 1480.)
// Grid = 256 = 1 block/CU anyway, so the padding costs zero real occupancy.
#define LPOOL_FLOATS 21504   // 86016 B > 81920 B threshold

__device__ __forceinline__ float fast_sigmoid(float v) {
    return 1.f / (1.f + __expf(-v));
}
// quad_perm butterflies (VALU DPP)
__device__ __forceinline__ float quad_xor1(float v) {
    return __int_as_float(__builtin_amdgcn_update_dpp(0, __float_as_int(v), 0xB1, 0xF, 0xF, true)); // [1,0,3,2]
}
__device__ __forceinline__ float quad_xor2(float v) {
    return __int_as_float(__builtin_amdgcn_update_dpp(0, __float_as_int(v), 0x4E, 0xF, 0xF, true)); // [2,3,0,1]
}
// lane l <-> l^4 (crosses quads, within 8-lane unit group)
__device__ __forceinline__ float swz_xor4(float v) {
    return __int_as_float(__builtin_amdgcn_ds_swizzle(__float_as_int(v), 0x101F));
}

__attribute__((amdgpu_flat_work_group_size(NTHR, NTHR), amdgpu_waves_per_eu(4, 4)))
__global__ void gru_persistent(const float* __restrict__ mfcc0,
                               const float* __restrict__ mfcc1,
                               const float* __restrict__ mfcc2,
                               const float* __restrict__ len0,
                               const float* __restrict__ W_ih,
                               const float* __restrict__ W_hh,
                               const float* __restrict__ b_ih,
                               const float* __restrict__ b_hh,
                               const float* __restrict__ W_out,
                               const float* __restrict__ b_out,
                               float* __restrict__ out)
{
    const int b   = blockIdx.x;
    const int tid = threadIdx.x;

    __shared__ __align__(16) float LPOOL[LPOOL_FLOATS];
    // sub-buffer layout inside the pool (all accesses go through these):
    float (*Vh2)[HPAD2] = (float (*)[HPAD2]) (LPOOL);            // 2*160 @ 0
    float (*gib)[304]   = (float (*)[304])   (LPOOL + 320);      // 2*304 @ 320
    float (*xbuf)[40]   = (float (*)[40])    (LPOOL + 928);      // 2*40  @ 928
    float *feat         =                    (LPOOL + 1008);     // 200   @ 1008

    const bool isCons = (tid < NCONS);

    // ---- consumer geometry: 8-lane group = hidden unit j, lane part p ----
    const int ju = tid >> 3;                    // 0..103 (consumers), idle >=100
    const int p  = tid & 7;                     // column part (16 cols each)
    const int j  = (ju < HDIM) ? ju : (HDIM - 1);

    // ---- producer geometry: rows (gA, gA+1) of the 300 gi rows ----
    const int q0 = isCons ? 0 : (tid - NCONS);  // 0..191, active <150
    const int gA = 2 * ((q0 < 150) ? q0 : 149);
    const int gB = gA + 1;

    // ---- SHARED weight registers: consumers w[0..11], producers w[0..19] ----
    float4 w[20];
    float  bh0 = 0.f, bh1 = 0.f, bh2 = 0.f;     // consumer: b_hh triple; producer: b_ih pair
    if (isCons) {
        const int base = 16 * p;
        #pragma unroll
        for (int rr = 0; rr < 3; ++rr) {
            const float* src = W_hh + (rr * HDIM + j) * HDIM;
            #pragma unroll
            for (int i = 0; i < 4; ++i) {
                const int c = base + 4 * i;
                float4 t;
                t.x = (c + 0 < HDIM) ? src[c + 0] : 0.f;
                t.y = (c + 1 < HDIM) ? src[c + 1] : 0.f;
                t.z = (c + 2 < HDIM) ? src[c + 2] : 0.f;
                t.w = (c + 3 < HDIM) ? src[c + 3] : 0.f;
                w[rr * 4 + i] = t;
            }
        }
        bh0 = b_hh[j]; bh1 = b_hh[HDIM + j]; bh2 = b_hh[2 * HDIM + j];
    } else {
        const float* sA = W_ih + gA * XDIM;
        const float* sB = W_ih + gB * XDIM;
        #pragma unroll
        for (int i = 0; i < 9; ++i) {
            w[i]      = make_float4(sA[4*i], sA[4*i+1], sA[4*i+2], sA[4*i+3]);
            w[10 + i] = make_float4(sB[4*i], sB[4*i+1], sB[4*i+2], sB[4*i+3]);
        }
        w[9]  = make_float4(sA[36], sA[37], sA[38], 0.f);   // pairs with xbuf[39]=0
        w[19] = make_float4(sB[36], sB[37], sB[38], 0.f);
        bh0 = b_ih[gA]; bh1 = b_ih[gB];
    }

    // ---- producer x streaming source ----
    const float* xsrc = mfcc0;
    int xoff = b * FIN;
    if (!isCons && q0 < XDIM) {
        const int f = q0 % FIN;
        xsrc = (q0 < FIN) ? mfcc0 : (q0 < 2 * FIN ? mfcc1 : mfcc2);
        xoff = b * FIN + f;
    }

    // ---- prologue: h0 = 0 (both buffers incl. skew pads), stage x(0)/x(1), gi(0) ----
    if (tid < HPAD2) { Vh2[0][tid] = 0.f; Vh2[1][tid] = 0.f; }
    if (tid < 40) {
        float v0 = 0.f, v1 = 0.f;
        if (tid < XDIM) {
            const int f = tid % FIN;
            const float* xs = (tid < FIN) ? mfcc0 : (tid < 2 * FIN ? mfcc1 : mfcc2);
            v0 = xs[b * FIN + f];
            v1 = xs[(size_t)BATCH * FIN + b * FIN + f];
        }
        xbuf[0][tid] = v0; xbuf[1][tid] = v1;
    }
    __syncthreads();
    if (!isCons && q0 < 150) {
        const float4* X4 = (const float4*)xbuf[0];
        float a0=0,a1=0,a2=0,a3=0, c0=0,c1=0,c2=0,c3=0;
        #pragma unroll
        for (int i = 0; i < 10; ++i) {
            const float4 vv = X4[i];
            a0=fmaf(w[i].x,vv.x,a0);      a1=fmaf(w[i].y,vv.y,a1);
            a2=fmaf(w[i].z,vv.z,a2);      a3=fmaf(w[i].w,vv.w,a3);
            c0=fmaf(w[10+i].x,vv.x,c0);   c1=fmaf(w[10+i].y,vv.y,c1);
            c2=fmaf(w[10+i].z,vv.z,c2);   c3=fmaf(w[10+i].w,vv.w,c3);
        }
        gib[0][gA] = bh0 + ((a0+a1)+(a2+a3));
        gib[0][gB] = bh1 + ((c0+c1)+(c2+c3));
    }
    __syncthreads();

    float hreg = 0.f;                 // h_j, replicated in all 8 unit lanes
    float sum = 0.f, mx = -INFINITY;
    const int hdst = SLDS * (j >> 4) + (j & 15);   // col j LDS address

    for (int t = 0; t < T_STEPS; ++t) {
        const int cur = t & 1;
        const int nxt = cur ^ 1;

        if (isCons) {
            // ---- GEMV part: 4 bcast float4 reads (skewed banks), 3 gates x 16 cols ----
            const float4* V4 = (const float4*)(Vh2[cur] + SLDS * p);
            float a0=0,a1=0,a2=0,a3=0, b0=0,b1=0,b2=0,b3=0, c0=0,c1=0,c2=0,c3=0;
            #pragma unroll
            for (int i = 0; i < 4; ++i) {
                const float4 vv = V4[i];
                a0=fmaf(w[i].x,vv.x,a0);      a1=fmaf(w[i].y,vv.y,a1);
                a2=fmaf(w[i].z,vv.z,a2);      a3=fmaf(w[i].w,vv.w,a3);
                b0=fmaf(w[4+i].x,vv.x,b0);    b1=fmaf(w[4+i].y,vv.y,b1);
                b2=fmaf(w[4+i].z,vv.z,b2);    b3=fmaf(w[4+i].w,vv.w,b3);
                c0=fmaf(w[8+i].x,vv.x,c0);    c1=fmaf(w[8+i].y,vv.y,c1);
                c2=fmaf(w[8+i].z,vv.z,c2);    c3=fmaf(w[8+i].w,vv.w,c3);
            }
            float s0 = (a0+a1)+(a2+a3);
            float s1 = (b0+b1)+(b2+b3);
            float s2 = (c0+c1)+(c2+c3);
            // ---- 8-lane butterfly: 2x DPP quad + 1x ds_swizzle xor4 ----
            s0 += quad_xor1(s0); s1 += quad_xor1(s1); s2 += quad_xor1(s2);
            s0 += quad_xor2(s0); s1 += quad_xor2(s1); s2 += quad_xor2(s2);
            s0 += swz_xor4(s0);  s1 += swz_xor4(s1);  s2 += swz_xor4(s2);
            // ---- gates + state update, fully in-register ----
            const float gr = gib[cur][j];
            const float gz = gib[cur][HDIM + j];
            const float gn = gib[cur][2 * HDIM + j];
            const float rg = fast_sigmoid(gr + s0 + bh0);
            const float zg = fast_sigmoid(gz + s1 + bh1);
            const float na = fmaf(rg, s2 + bh2, gn);
            const float ng = fmaf(2.f, fast_sigmoid(2.f * na), -1.f);  // tanh
            const float hv = fmaf(zg, hreg - ng, ng);              // (1-z)*n + z*h
            hreg = hv;
            sum += hv; mx = fmaxf(mx, hv);
            if (p == 0 && ju < HDIM) Vh2[nxt][hdst] = hv;          // publish h(t+1)
        } else {
            // ---- producers: prefetch x(t+2), compute gi(t+1) into gib[nxt] ----
            float xv = 0.f;
            const bool doX = (q0 < XDIM) && (t + 2 < T_STEPS);
            if (doX) xv = xsrc[(size_t)(t + 2) * (BATCH * FIN) + xoff];
            if ((t + 1 < T_STEPS) && q0 < 150) {
                const float4* X4 = (const float4*)xbuf[nxt];
                float a0=0,a1=0,a2=0,a3=0, c0=0,c1=0,c2=0,c3=0;
                #pragma unroll
                for (int i = 0; i < 10; ++i) {
                    const float4 vv = X4[i];
                    a0=fmaf(w[i].x,vv.x,a0);      a1=fmaf(w[i].y,vv.y,a1);
                    a2=fmaf(w[i].z,vv.z,a2);      a3=fmaf(w[i].w,vv.w,a3);
                    c0=fmaf(w[10+i].x,vv.x,c0);   c1=fmaf(w[10+i].y,vv.y,c1);
                    c2=fmaf(w[10+i].z,vv.z,c2);   c3=fmaf(w[10+i].w,vv.w,c3);
                }
                gib[nxt][gA] = bh0 + ((a0+a1)+(a2+a3));
                gib[nxt][gB] = bh1 + ((c0+c1)+(c2+c3));
            }
            if (doX) xbuf[cur][q0] = xv;
        }
        __syncthreads();
    }

    // ---- pooling + output linear ----
    if (isCons && p == 0 && ju < HDIM) {
        feat[ju]        = sum / len0[b];
        feat[HDIM + ju] = mx;
    }
    __syncthreads();

    if (tid < NCLS) {
        float acc = b_out[tid];
        #pragma unroll 4
        for (int k = 0; k < 2 * HDIM; ++k)
            acc = fmaf(W_out[tid * 2 * HDIM + k], feat[k], acc);
        out[b * NCLS + tid] = acc;
    }
}

extern "C" void kernel_launch(void* const* d_in, const int* in_sizes, int n_in,
                              void* d_out, int out_size, void* d_ws, size_t ws_size,
                              hipStream_t stream)
{
    const float* mfcc0 = (const float*)d_in[0];
    const float* mfcc1 = (const float*)d_in[1];
    const float* mfcc2 = (const float*)d_in[2];
    const float* len0  = (const float*)d_in[3];
    const float* W_ih  = (const float*)d_in[4];
    const float* W_hh  = (const float*)d_in[5];
    const float* b_ih  = (const float*)d_in[6];
    const float* b_hh  = (const float*)d_in[7];
    const float* W_out = (const float*)d_in[8];
    const float* b_out = (const float*)d_in[9];
    float* out = (float*)d_out;

    gru_persistent<<<BATCH, NTHR, 0, stream>>>(
        mfcc0, mfcc1, mfcc2, len0, W_ih, W_hh, b_ih, b_hh, W_out, b_out, out);
}

// Round 9
// 735.314 us; speedup vs baseline: 2.0132x; 2.0052x over previous
//
#include <hip/hip_runtime.h>
#include <math.h>

// T=1000, B=256, F_IN=13 x3 -> 39 features, H=100, gates r,z,n (3H=300), 20 classes
#define T_STEPS 1000
#define BATCH   256
#define FIN     13
#define XDIM    39
#define HDIM    100
#define NCLS    20

#define NCONS   448     // 7 consumer waves: quad per hidden unit, 4 col-parts/lane
#define NTHR    640     // + 3 producer waves (192 threads, 150 active)
#define HPAD    112     // h padded to 4*28 for uniform float4 reads
#define PCOLS   28      // columns per lane part

__device__ __forceinline__ float fast_sigmoid(float v) {
    return 1.f / (1.f + __expf(-v));
}
// quad_perm butterflies (VALU DPP; all 4 quad lanes active in consumer waves)
__device__ __forceinline__ float quad_xor1(float v) {
    return __int_as_float(__builtin_amdgcn_update_dpp(0, __float_as_int(v), 0xB1, 0xF, 0xF, true)); // [1,0,3,2]
}
__device__ __forceinline__ float quad_xor2(float v) {
    return __int_as_float(__builtin_amdgcn_update_dpp(0, __float_as_int(v), 0x4E, 0xF, 0xF, true)); // [2,3,0,1]
}

// R4-R8 lesson: B=1024 pins the allocator at 64 VGPR (spill, 1480us) no matter
// what attribute we throw at it. Dead end. This round: the PROVEN R3 structure
// (B=640, 756us, VGPR 84, no spill) with the allocation theory applied to IT:
// R3's VGPR=84 < ~115 live need means the compiler parks overflow in AGPRs
// (gfx950 unified file) and shuttles via v_accvgpr_read/write -> inflated VALU
// (explains VALUBusy 81% for ~135 real ops). amdgpu_waves_per_eu(2,3): 10 waves
// need exactly 3/SIMD, so max=3 is free and raises the VGPR budget to 512/3=170.
// + sigma-form tanh (no clamp, validated R4-R8) + gib b128 read hoisted early.
__attribute__((amdgpu_flat_work_group_size(NTHR, NTHR), amdgpu_waves_per_eu(2, 3)))
__global__ void gru_persistent(const float* __restrict__ mfcc0,
                               const float* __restrict__ mfcc1,
                               const float* __restrict__ mfcc2,
                               const float* __restrict__ len0,
                               const float* __restrict__ W_ih,
                               const float* __restrict__ W_hh,
                               const float* __restrict__ b_ih,
                               const float* __restrict__ b_hh,
                               const float* __restrict__ W_out,
                               const float* __restrict__ b_out,
                               float* __restrict__ out)
{
    const int b   = blockIdx.x;
    const int tid = threadIdx.x;

    __shared__ __align__(16) float Vh[2][HPAD];       // h(t), pads [100..112) stay 0
    __shared__ __align__(16) float gib[2][4 * HDIM];  // gi transposed: [j][r,z,n,pad]
    __shared__ __align__(16) float xbuf[2][40];       // x staging (39 + zero pad)
    __shared__ float feat[2 * HDIM];

    const bool isCons = (tid < NCONS);

    // ---- consumer geometry: quad q = hidden unit j, lane part p ----
    const int q  = tid >> 2;                    // 0..111 (consumers), idle q>=100
    const int p  = tid & 3;                     // column part
    const int j  = (q < HDIM) ? q : (HDIM - 1); // clamped unit id

    // ---- producer geometry: rows (gA, gA+1) of the 300 gi rows ----
    const int q0 = isCons ? 0 : (tid - NCONS);  // 0..191, active <150
    const int gA = 2 * ((q0 < 150) ? q0 : 149);
    const int gB = gA + 1;

    // ---- SHARED weight registers: consumers w[0..20], producers w[0..19] ----
    float4 w[21];
    float  bh0 = 0.f, bh1 = 0.f, bh2 = 0.f;     // consumer: b_hh triple; producer: b_ih pair
    int    ofA = 0, ofB = 0;                    // producer gib write offsets
    if (isCons) {
        const int base = PCOLS * p;
        #pragma unroll
        for (int rr = 0; rr < 3; ++rr) {
            const float* src = W_hh + (rr * HDIM + j) * HDIM;
            #pragma unroll
            for (int i = 0; i < 7; ++i) {
                const int c = base + 4 * i;
                float4 t;
                t.x = (c + 0 < HDIM) ? src[c + 0] : 0.f;
                t.y = (c + 1 < HDIM) ? src[c + 1] : 0.f;
                t.z = (c + 2 < HDIM) ? src[c + 2] : 0.f;
                t.w = (c + 3 < HDIM) ? src[c + 3] : 0.f;
                w[rr * 7 + i] = t;
            }
        }
        bh0 = b_hh[j]; bh1 = b_hh[HDIM + j]; bh2 = b_hh[2 * HDIM + j];
    } else {
        const float* sA = W_ih + gA * XDIM;
        const float* sB = W_ih + gB * XDIM;
        #pragma unroll
        for (int i = 0; i < 9; ++i) {
            w[i]      = make_float4(sA[4*i], sA[4*i+1], sA[4*i+2], sA[4*i+3]);
            w[10 + i] = make_float4(sB[4*i], sB[4*i+1], sB[4*i+2], sB[4*i+3]);
        }
        w[9]  = make_float4(sA[36], sA[37], sA[38], 0.f);   // pairs with xbuf[39]=0
        w[19] = make_float4(sB[36], sB[37], sB[38], 0.f);
        w[20] = make_float4(0, 0, 0, 0);
        bh0 = b_ih[gA]; bh1 = b_ih[gB];
        ofA = (gA % HDIM) * 4 + gA / HDIM;
        ofB = (gB % HDIM) * 4 + gB / HDIM;
    }

    // ---- producer x streaming source ----
    const float* xsrc = mfcc0;
    int xoff = b * FIN;
    if (!isCons && q0 < XDIM) {
        const int f = q0 % FIN;
        xsrc = (q0 < FIN) ? mfcc0 : (q0 < 2 * FIN ? mfcc1 : mfcc2);
        xoff = b * FIN + f;
    }

    // ---- prologue: h0 = 0 (both buffers, pads included), stage x(0)/x(1), gi(0) ----
    if (tid < HPAD) { Vh[0][tid] = 0.f; Vh[1][tid] = 0.f; }
    if (tid < 40) {
        float v0 = 0.f, v1 = 0.f;
        if (tid < XDIM) {
            const int f = tid % FIN;
            const float* xs = (tid < FIN) ? mfcc0 : (tid < 2 * FIN ? mfcc1 : mfcc2);
            v0 = xs[b * FIN + f];
            v1 = xs[(size_t)BATCH * FIN + b * FIN + f];
        }
        xbuf[0][tid] = v0; xbuf[1][tid] = v1;
    }
    __syncthreads();
    if (!isCons && q0 < 150) {
        const float4* X4 = (const float4*)xbuf[0];
        float a0=0,a1=0,a2=0,a3=0, c0=0,c1=0,c2=0,c3=0;
        #pragma unroll
        for (int i = 0; i < 10; ++i) {
            const float4 vv = X4[i];
            a0=fmaf(w[i].x,vv.x,a0);      a1=fmaf(w[i].y,vv.y,a1);
            a2=fmaf(w[i].z,vv.z,a2);      a3=fmaf(w[i].w,vv.w,a3);
            c0=fmaf(w[10+i].x,vv.x,c0);   c1=fmaf(w[10+i].y,vv.y,c1);
            c2=fmaf(w[10+i].z,vv.z,c2);   c3=fmaf(w[10+i].w,vv.w,c3);
        }
        gib[0][ofA] = bh0 + ((a0+a1)+(a2+a3));
        gib[0][ofB] = bh1 + ((c0+c1)+(c2+c3));
    }
    __syncthreads();

    float hreg = 0.f;                 // h_j, kept in registers (all 4 quad lanes)
    float sum = 0.f, mx = -INFINITY;

    for (int t = 0; t < T_STEPS; ++t) {
        const int cur = t & 1;
        const int nxt = cur ^ 1;

        if (isCons) {
            // ---- gi read issued FIRST (in-order LDS returns -> ready early) ----
            const float4 g4 = ((const float4*)gib[cur])[j];        // (i_r, i_z, i_n, -)
            // ---- GEMV part: 7 bcast float4 reads, 3 gate rows x 28 cols ----
            const float4* V4 = (const float4*)(Vh[cur] + p * PCOLS);
            float a0=0,a1=0,a2=0,a3=0, b0=0,b1=0,b2=0,b3=0, c0=0,c1=0,c2=0,c3=0;
            #pragma unroll
            for (int i = 0; i < 7; ++i) {
                const float4 vv = V4[i];
                a0=fmaf(w[i].x,vv.x,a0);      a1=fmaf(w[i].y,vv.y,a1);
                a2=fmaf(w[i].z,vv.z,a2);      a3=fmaf(w[i].w,vv.w,a3);
                b0=fmaf(w[7+i].x,vv.x,b0);    b1=fmaf(w[7+i].y,vv.y,b1);
                b2=fmaf(w[7+i].z,vv.z,b2);    b3=fmaf(w[7+i].w,vv.w,b3);
                c0=fmaf(w[14+i].x,vv.x,c0);   c1=fmaf(w[14+i].y,vv.y,c1);
                c2=fmaf(w[14+i].z,vv.z,c2);   c3=fmaf(w[14+i].w,vv.w,c3);
            }
            float s0 = (a0+a1)+(a2+a3);
            float s1 = (b0+b1)+(b2+b3);
            float s2 = (c0+c1)+(c2+c3);
            // ---- quad butterfly (DPP, VALU pipe): all 4 lanes get full sums ----
            s0 += quad_xor1(s0); s1 += quad_xor1(s1); s2 += quad_xor1(s2);
            s0 += quad_xor2(s0); s1 += quad_xor2(s1); s2 += quad_xor2(s2);
            // ---- gates + state update, fully in-register ----
            const float rg = fast_sigmoid(g4.x + s0 + bh0);
            const float zg = fast_sigmoid(g4.y + s1 + bh1);
            const float na = fmaf(rg, s2 + bh2, g4.z);
            const float ng = fmaf(2.f, fast_sigmoid(2.f * na), -1.f); // tanh, no clamp
            const float hv = fmaf(zg, hreg - ng, ng);              // (1-z)*n + z*h
            hreg = hv;
            sum += hv; mx = fmaxf(mx, hv);
            if (p == 0 && q < HDIM) Vh[nxt][q] = hv;               // publish h(t+1)
        } else {
            // ---- producers: prefetch x(t+2), compute gi(t+1) into gib[nxt] ----
            float xv = 0.f;
            const bool doX = (q0 < XDIM) && (t + 2 < T_STEPS);
            if (doX) xv = xsrc[(size_t)(t + 2) * (BATCH * FIN) + xoff];
            if ((t + 1 < T_STEPS) && q0 < 150) {
                const float4* X4 = (const float4*)xbuf[nxt];
                float a0=0,a1=0,a2=0,a3=0, c0=0,c1=0,c2=0,c3=0;
                #pragma unroll
                for (int i = 0; i < 10; ++i) {
                    const float4 vv = X4[i];
                    a0=fmaf(w[i].x,vv.x,a0);      a1=fmaf(w[i].y,vv.y,a1);
                    a2=fmaf(w[i].z,vv.z,a2);      a3=fmaf(w[i].w,vv.w,a3);
                    c0=fmaf(w[10+i].x,vv.x,c0);   c1=fmaf(w[10+i].y,vv.y,c1);
                    c2=fmaf(w[10+i].z,vv.z,c2);   c3=fmaf(w[10+i].w,vv.w,c3);
                }
                gib[nxt][ofA] = bh0 + ((a0+a1)+(a2+a3));
                gib[nxt][ofB] = bh1 + ((c0+c1)+(c2+c3));
            }
            if (doX) xbuf[cur][q0] = xv;
        }
        __syncthreads();
    }

    // ---- pooling + output linear ----
    if (isCons && p == 0 && q < HDIM) {
        feat[q]        = sum / len0[b];
        feat[HDIM + q] = mx;
    }
    __syncthreads();

    if (tid < NCLS) {
        float acc = b_out[tid];
        #pragma unroll 4
        for (int k = 0; k < 2 * HDIM; ++k)
            acc = fmaf(W_out[tid * 2 * HDIM + k], feat[k], acc);
        out[b * NCLS + tid] = acc;
    }
}

extern "C" void kernel_launch(void* const* d_in, const int* in_sizes, int n_in,
                              void* d_out, int out_size, void* d_ws, size_t ws_size,
                              hipStream_t stream)
{
    const float* mfcc0 = (const float*)d_in[0];
    const float* mfcc1 = (const float*)d_in[1];
    const float* mfcc2 = (const float*)d_in[2];
    const float* len0  = (const float*)d_in[3];
    const float* W_ih  = (const float*)d_in[4];
    const float* W_hh  = (const float*)d_in[5];
    const float* b_ih  = (const float*)d_in[6];
    const float* b_hh  = (const float*)d_in[7];
    const float* W_out = (const float*)d_in[8];
    const float* b_out = (const float*)d_in[9];
    float* out = (float*)d_out;

    gru_persistent<<<BATCH, NTHR, 0, stream>>>(
        mfcc0, mfcc1, mfcc2, len0, W_ih, W_hh, b_ih, b_hh, W_out, b_out, out);
}